// Round 1
// baseline (3964.058 us; speedup 1.0000x reference)
//
#include <hip/hip_runtime.h>

#define NN 50000
#define EE 800000
#define NX 48
#define VX 16
#define NEc 32
#define VEc 16
#define HH 32

#ifdef __HIP_PLATFORM_AMD__
#define ATOMIC_ADD_F32(p, v) unsafeAtomicAdd((p), (v))
#else
#define ATOMIC_ADD_F32(p, v) atomicAdd((p), (v))
#endif

// ws layout (floats): [0..256) scalars (0=S1, 1=S2); [256..256+NN*96) upd; then node2 (NN*96)

// ---------------- Node GVP: s1=LN(gvp_s+s0), V1=gvp_V+V0 (unscaled), accumulate sumsq(V1)
__global__ __launch_bounds__(256) void k_node(
    const float* __restrict__ na,
    const float* __restrict__ Wh,   // 32x16
    const float* __restrict__ Wmu,  // 16x32
    const float* __restrict__ Wmw,  // 48x80
    const float* __restrict__ Wmb,  // 48
    const float* __restrict__ lng,
    const float* __restrict__ lnb,
    float* __restrict__ node2,
    float* __restrict__ S1)
{
    __shared__ float X[32][129];   // 0..47 s0 | 48..79 sh | 80..127 s1
    __shared__ float VC[32][49];   // d*16+v
    __shared__ float VH[32][97];   // d*32+h
    __shared__ float VMU[32][49];  // m*3+d
    __shared__ float MEANs[32], INVs[32];
    int tid = threadIdx.x;
    int nb = blockIdx.x * 32;
    for (int idx = tid; idx < 32*96; idx += 256) {
        int t = idx / 96, j = idx % 96;
        int n = nb + t;
        if (n < NN) {
            float v = na[(long)n*96 + j];
            if (j < 48) X[t][j] = v;
            else { int p = j - 48; VC[t][(p%3)*16 + p/3] = v; }
        }
    }
    __syncthreads();
    int t = tid & 31, c = tid >> 5;
    // Vh = Wh @ V0 : 96 outputs/node
    for (int j = 0; j < 12; j++) {
        int o = c*12 + j, d = o >> 5, h = o & 31;
        float acc = 0.f;
        #pragma unroll
        for (int v = 0; v < 16; v++) acc += Wh[h*16+v] * VC[t][d*16+v];
        VH[t][d*32+h] = acc;
    }
    __syncthreads();
    // sh = ||Vh||
    for (int j = 0; j < 4; j++) {
        int h = c*4 + j;
        float a = VH[t][h], b = VH[t][32+h], d2 = VH[t][64+h];
        X[t][48+h] = sqrtf(a*a + b*b + d2*d2);
    }
    __syncthreads();
    // Vmu = Wmu @ Vh : 48 outputs
    for (int j = 0; j < 6; j++) {
        int o = c*6 + j, m = o/3, d = o%3;
        float acc = 0.f;
        #pragma unroll 8
        for (int h = 0; h < 32; h++) acc += Wmu[m*32+h] * VH[t][d*32+h];
        VMU[t][o] = acc;
    }
    __syncthreads();
    // s1 = relu(W@[s0,sh]+b)+s0
    for (int j = 0; j < 6; j++) {
        int i = c*6 + j;
        float acc = Wmb[i];
        const float* wr = Wmw + i*80;
        #pragma unroll 8
        for (int k = 0; k < 80; k++) acc += wr[k] * X[t][k];
        X[t][80+i] = fmaxf(acc, 0.f) + X[t][i];
    }
    __syncthreads();
    if (tid < 32) {
        float m = 0.f;
        #pragma unroll 8
        for (int i = 0; i < 48; i++) m += X[tid][80+i];
        m *= (1.f/48.f);
        float v = 0.f;
        #pragma unroll 8
        for (int i = 0; i < 48; i++) { float d = X[tid][80+i] - m; v += d*d; }
        MEANs[tid] = m;
        INVs[tid] = rsqrtf(v*(1.f/48.f) + 1e-5f);
    }
    __syncthreads();
    int n = nb + t;
    float ss = 0.f;
    if (n < NN) {
        float* o = node2 + (long)n*96;
        for (int j = 0; j < 6; j++) {
            int i = c*6 + j;
            o[i] = (X[t][80+i] - MEANs[t]) * INVs[t] * lng[i] + lnb[i];
        }
        for (int j = 0; j < 2; j++) {
            int m = c*2 + j;
            float a = VMU[t][m*3], b = VMU[t][m*3+1], cc = VMU[t][m*3+2];
            float nm = sqrtf(a*a + b*b + cc*cc);
            float x = nm*a + VC[t][0*16+m];
            float y = nm*b + VC[t][1*16+m];
            float z = nm*cc + VC[t][2*16+m];
            o[48+m*3] = x; o[48+m*3+1] = y; o[48+m*3+2] = z;
            ss += x*x + y*y + z*z;
        }
    }
    #pragma unroll
    for (int off = 32; off > 0; off >>= 1) ss += __shfl_down(ss, off, 64);
    if ((tid & 63) == 0) atomicAdd(S1, ss);
}

// ---------------- scale node2 V-part by global gvp_ln factor
__global__ void k_scale(float* __restrict__ node2, const float* __restrict__ S1)
{
    int i = blockIdx.x*256 + threadIdx.x;
    if (i < NN*48) {
        float scale = rsqrtf(sqrtf(*S1) * (1.f/16.f));
        int n = i/48, p = i%48;
        node2[(long)n*96 + 48 + p] *= scale;
    }
}

// ---------------- Edge kernel: gve GVP -> atomic scatter into upd; ge GVP -> out1
__global__ __launch_bounds__(256) void k_edge(
    const float* __restrict__ ea, const int* __restrict__ eidx,
    const float* __restrict__ node2,
    const float* __restrict__ gveWh,  // 32x32
    const float* __restrict__ gveWmu, // 16x32
    const float* __restrict__ gveWmw, // 48x112
    const float* __restrict__ gveWmb, // 48
    const float* __restrict__ geWh,   // 32x32
    const float* __restrict__ geWmu,  // 16x32
    const float* __restrict__ geWmw,  // 32x112
    const float* __restrict__ geWmb,  // 32
    float* __restrict__ upd, float* __restrict__ out1)
{
    __shared__ float X[32][113];   // 0..47 s_n | 48..79 s_e | 80..111 sh
    __shared__ float VC[32][97];   // d*32 + vv  (vv<16 node, >=16 edge)
    __shared__ float VH[32][97];   // d*32 + h
    __shared__ float VMU[32][49];  // m*3+d
    __shared__ int SRC[32], DST[32];
    int tid = threadIdx.x;
    long e0 = (long)blockIdx.x * 32;
    if (tid < 32) {
        long e = e0 + tid;
        DST[tid] = eidx[e];
        SRC[tid] = eidx[EE + e];
    }
    __syncthreads();
    // stage edge attrs
    for (int idx = tid; idx < 32*80; idx += 256) {
        int t = idx / 80, j = idx % 80;
        float v = ea[(e0 + t)*80 + j];
        if (j < 32) X[t][48+j] = v;
        else { int p = j - 32; VC[t][(p%3)*32 + 16 + p/3] = v; }
    }
    // gather node2 rows
    for (int idx = tid; idx < 32*96; idx += 256) {
        int t = idx / 96, j = idx % 96;
        float v = node2[(long)SRC[t]*96 + j];
        if (j < 48) X[t][j] = v;
        else { int p = j - 48; VC[t][(p%3)*32 + p/3] = v; }
    }
    __syncthreads();
    int t = tid & 31, c = tid >> 5;
    // ======== gve ========
    for (int j = 0; j < 12; j++) {
        int o = c*12 + j, d = o >> 5, h = o & 31;
        float acc = 0.f;
        #pragma unroll 8
        for (int v = 0; v < 32; v++) acc += gveWh[h*32+v] * VC[t][d*32+v];
        VH[t][d*32+h] = acc;
    }
    __syncthreads();
    for (int j = 0; j < 4; j++) {
        int h = c*4 + j;
        float a = VH[t][h], b = VH[t][32+h], d2 = VH[t][64+h];
        X[t][80+h] = sqrtf(a*a + b*b + d2*d2);
    }
    __syncthreads();
    for (int j = 0; j < 6; j++) {
        int o = c*6 + j, m = o/3, d = o%3;
        float acc = 0.f;
        #pragma unroll 8
        for (int h = 0; h < 32; h++) acc += gveWmu[m*32+h] * VH[t][d*32+h];
        VMU[t][o] = acc;
    }
    __syncthreads();
    int dst = DST[t];
    float* urow = upd + (long)dst * 96;
    // vector message: relu(|Vmu|)*Vmu = |Vmu|*Vmu
    for (int j = 0; j < 2; j++) {
        int m = c*2 + j;
        float a = VMU[t][m*3], b = VMU[t][m*3+1], cc = VMU[t][m*3+2];
        float nm = sqrtf(a*a + b*b + cc*cc);
        ATOMIC_ADD_F32(&urow[48 + m*3 + 0], nm*a);
        ATOMIC_ADD_F32(&urow[48 + m*3 + 1], nm*b);
        ATOMIC_ADD_F32(&urow[48 + m*3 + 2], nm*cc);
    }
    // scalar message
    for (int j = 0; j < 6; j++) {
        int i = c*6 + j;
        float acc = gveWmb[i];
        const float* wr = gveWmw + i*112;
        #pragma unroll 8
        for (int k = 0; k < 112; k++) acc += wr[k] * X[t][k];
        ATOMIC_ADD_F32(&urow[i], fmaxf(acc, 0.f));
    }
    __syncthreads();
    // ======== ge ========
    for (int j = 0; j < 12; j++) {
        int o = c*12 + j, d = o >> 5, h = o & 31;
        float acc = 0.f;
        #pragma unroll 8
        for (int v = 0; v < 32; v++) acc += geWh[h*32+v] * VC[t][d*32+v];
        VH[t][d*32+h] = acc;
    }
    __syncthreads();
    for (int j = 0; j < 4; j++) {
        int h = c*4 + j;
        float a = VH[t][h], b = VH[t][32+h], d2 = VH[t][64+h];
        X[t][80+h] = sqrtf(a*a + b*b + d2*d2);
    }
    __syncthreads();
    for (int j = 0; j < 6; j++) {
        int o = c*6 + j, m = o/3, d = o%3;
        float acc = 0.f;
        #pragma unroll 8
        for (int h = 0; h < 32; h++) acc += geWmu[m*32+h] * VH[t][d*32+h];
        VMU[t][o] = acc;
    }
    __syncthreads();
    float* orow = out1 + (e0 + t)*80;
    for (int j = 0; j < 2; j++) {
        int m = c*2 + j;
        float a = VMU[t][m*3], b = VMU[t][m*3+1], cc = VMU[t][m*3+2];
        float nm = sqrtf(a*a + b*b + cc*cc);
        orow[32 + m*3 + 0] = nm*a;
        orow[32 + m*3 + 1] = nm*b;
        orow[32 + m*3 + 2] = nm*cc;
    }
    for (int j = 0; j < 4; j++) {
        int i = c*4 + j;
        float acc = geWmb[i];
        const float* wr = geWmw + i*112;
        #pragma unroll 8
        for (int k = 0; k < 112; k++) acc += wr[k] * X[t][k];
        orow[i] = fmaxf(acc, 0.f);
    }
}

// ---------------- node update: su=LN(upd_s/30+s1), Vu=upd_V/30+V1 (stash unscaled), sumsq
__global__ __launch_bounds__(256) void k_update(
    const float* __restrict__ upd, const float* __restrict__ node2,
    const float* __restrict__ lng, const float* __restrict__ lnb,
    float* __restrict__ out0, float* __restrict__ S2)
{
    int n = blockIdx.x*256 + threadIdx.x;
    float ss = 0.f;
    if (n < NN) {
        const float* u = upd + (long)n*96;
        const float* p2 = node2 + (long)n*96;
        float su[48];
        float mean = 0.f;
        #pragma unroll
        for (int i = 0; i < 48; i++) { float v = u[i]*(1.f/30.f) + p2[i]; su[i] = v; mean += v; }
        mean *= (1.f/48.f);
        float var = 0.f;
        #pragma unroll
        for (int i = 0; i < 48; i++) { float d = su[i] - mean; var += d*d; }
        float inv = rsqrtf(var*(1.f/48.f) + 1e-5f);
        float* o = out0 + (long)n*96;
        #pragma unroll
        for (int i = 0; i < 48; i++) o[i] = p2[i] + (su[i]-mean)*inv*lng[i] + lnb[i];
        #pragma unroll
        for (int p = 0; p < 48; p++) {
            float v = u[48+p]*(1.f/30.f) + p2[48+p];
            o[48+p] = v;           // stash unscaled Vu
            ss += v*v;
        }
    }
    #pragma unroll
    for (int off = 32; off > 0; off >>= 1) ss += __shfl_down(ss, off, 64);
    if ((threadIdx.x & 63) == 0) atomicAdd(S2, ss);
}

// ---------------- finalize V part of output 0
__global__ void k_fin(float* __restrict__ out0, const float* __restrict__ node2,
                      const float* __restrict__ S2)
{
    int i = blockIdx.x*256 + threadIdx.x;
    if (i < NN*48) {
        float scale = rsqrtf(sqrtf(*S2) * (1.f/16.f));
        int n = i/48, p = i%48;
        long off = (long)n*96 + 48 + p;
        out0[off] = node2[off] + out0[off]*scale;
    }
}

extern "C" void kernel_launch(void* const* d_in, const int* in_sizes, int n_in,
                              void* d_out, int out_size, void* d_ws, size_t ws_size,
                              hipStream_t stream)
{
    const float* na      = (const float*)d_in[0];
    const float* ea      = (const float*)d_in[1];
    const int*   eidx    = (const int*)  d_in[2];
    const float* gv_Wh   = (const float*)d_in[3];
    const float* gv_Wmu  = (const float*)d_in[4];
    const float* gv_Wmw  = (const float*)d_in[5];
    const float* gv_Wmb  = (const float*)d_in[6];
    const float* gve_Wh  = (const float*)d_in[7];
    const float* gve_Wmu = (const float*)d_in[8];
    const float* gve_Wmw = (const float*)d_in[9];
    const float* gve_Wmb = (const float*)d_in[10];
    const float* ge_Wh   = (const float*)d_in[11];
    const float* ge_Wmu  = (const float*)d_in[12];
    const float* ge_Wmw  = (const float*)d_in[13];
    const float* ge_Wmb  = (const float*)d_in[14];
    const float* lng     = (const float*)d_in[15];
    const float* lnb     = (const float*)d_in[16];

    float* ws    = (float*)d_ws;
    float* S     = ws;                         // [0]=S1, [1]=S2
    float* upd   = ws + 256;
    float* node2 = ws + 256 + (size_t)NN*96;
    float* out0  = (float*)d_out;
    float* out1  = out0 + (size_t)NN*96;

    // zero scalars + upd accumulator (ws is poisoned 0xAA before every launch)
    hipMemsetAsync(d_ws, 0, (256 + (size_t)NN*96) * sizeof(float), stream);

    k_node<<<(NN + 31)/32, 256, 0, stream>>>(na, gv_Wh, gv_Wmu, gv_Wmw, gv_Wmb,
                                             lng, lnb, node2, S);
    k_scale<<<(NN*48 + 255)/256, 256, 0, stream>>>(node2, S);
    k_edge<<<EE/32, 256, 0, stream>>>(ea, eidx, node2,
                                      gve_Wh, gve_Wmu, gve_Wmw, gve_Wmb,
                                      ge_Wh, ge_Wmu, ge_Wmw, ge_Wmb,
                                      upd, out1);
    k_update<<<(NN + 255)/256, 256, 0, stream>>>(upd, node2, lng, lnb, out0, S + 1);
    k_fin<<<(NN*48 + 255)/256, 256, 0, stream>>>(out0, node2, S + 1);
}